// Round 9
// baseline (349.776 us; speedup 1.0000x reference)
//
#include <hip/hip_runtime.h>
#include <hip/hip_bf16.h>
#include <cstdint>

typedef __attribute__((ext_vector_type(8))) short short8;
typedef __attribute__((ext_vector_type(4))) short short4_t;
typedef __attribute__((ext_vector_type(4))) float f32x4;

#define MFMA16(a, b, c) __builtin_amdgcn_mfma_f32_16x16x32_bf16(a, b, c, 0, 0, 0)

__device__ __forceinline__ short f2b(float f) {
    union { float fp; unsigned u; } un; un.fp = f;
    unsigned r = un.u + 0x7fffu + ((un.u >> 16) & 1u);
    return (short)(r >> 16);
}

// gfx950 has NO __builtin_amdgcn_cvt_pk_bf16_f32 (learn_hip m240); use the
// HW instruction directly. RNE rounding == f2b. dst.lo=cvt(a), dst.hi=cvt(b).
__device__ __forceinline__ unsigned pk_bf16(float a, float b) {
    unsigned r;
    asm("v_cvt_pk_bf16_f32 %0, %1, %2" : "=v"(r) : "v"(a), "v"(b));
    return r;
}

union pk8_u { unsigned u4[4]; short8 s8; };
union pk4_u { unsigned u2[2]; short4_t s4; };
union cat8_u { short4_t s4[2]; short8 s8; };

typedef const __attribute__((address_space(1))) unsigned g_as1;
typedef __attribute__((address_space(3))) unsigned l_as3;
__device__ __forceinline__ void gll16(const ushort* g, ushort* l) {
    __builtin_amdgcn_global_load_lds((g_as1*)g, (l_as3*)l, 16, 0, 0);
}

// ---------------------------------------------------------------------------
// Merged converts (one launch): ids [0,8192) = fp32->bf16 of query/context,
// ids [8192,9216) = weight transpose+convert fp32 [k][n] -> bf16 [n][k].
// ---------------------------------------------------------------------------
__global__ __launch_bounds__(256) void cvt_all_kernel(
    const float* __restrict__ q, const float* __restrict__ c,
    ushort* __restrict__ qb, ushort* __restrict__ cb,
    const float* __restrict__ Wq, const float* __restrict__ Wk,
    const float* __restrict__ Wv, const float* __restrict__ Wo,
    ushort* __restrict__ wt)
{
    __shared__ float Ts[64 * 65];
    const int id = blockIdx.x;
    const int tid = threadIdx.x;

    if (id < 8192) {
        const float* src = (id >= 4096) ? c : q;
        ushort* dst = (id >= 4096) ? cb : qb;
        size_t i = ((size_t)(id & 4095) * 256 + tid) * 8;
        float4 v0 = *(const float4*)&src[i];
        float4 v1 = *(const float4*)&src[i + 4];
        uint4 o;
        o.x = pk_bf16(v0.x, v0.y); o.y = pk_bf16(v0.z, v0.w);
        o.z = pk_bf16(v1.x, v1.y); o.w = pk_bf16(v1.z, v1.w);
        *(uint4*)&dst[i] = o;
        return;
    }

    const int u = id - 8192;
    const int z = u >> 8;
    const float* W = (z == 0) ? Wq : (z == 1) ? Wk : (z == 2) ? Wv : Wo;
    ushort* WT = wt + (size_t)z * (1024 * 1024);
    const int n0 = (u & 15) * 64, k0 = ((u >> 4) & 15) * 64;

#pragma unroll
    for (int rr = 0; rr < 4; ++rr) {
        int uu = tid + rr * 256;
        int r = uu >> 4, cc = (uu & 15) * 4;
        float4 v = *(const float4*)&W[(size_t)(k0 + r) * 1024 + n0 + cc];
        Ts[r * 65 + cc + 0] = v.x; Ts[r * 65 + cc + 1] = v.y;
        Ts[r * 65 + cc + 2] = v.z; Ts[r * 65 + cc + 3] = v.w;
    }
    __syncthreads();
#pragma unroll
    for (int rr = 0; rr < 4; ++rr) {
        int uu = tid + rr * 256;
        int rn = uu >> 4, ck = (uu & 15) * 4;
        pk4_u o;
        o.u2[0] = pk_bf16(Ts[(ck + 0) * 65 + rn], Ts[(ck + 1) * 65 + rn]);
        o.u2[1] = pk_bf16(Ts[(ck + 2) * 65 + rn], Ts[(ck + 3) * 65 + rn]);
        *(short4_t*)&WT[(size_t)(n0 + rn) * 1024 + k0 + ck] = o.s4;
    }
}

// ---------------------------------------------------------------------------
// Q/K/V projection v3: A double-buffered in LDS (2x16KB=32KB, 4-5 blk/CU
// kept), B streamed DIRECT from L2 into registers (no LDS staging at all).
// R8 lesson: 48KB LDS -> 3 blk/CU killed barrier-latency hiding. Here the
// per-step vmcnt(0) drain covers only the A-prefetch, which has the whole
// compute phase to land (attn's proven pattern), and B loads are plain 16B
// global reads of the L2-resident, XCD-chunked weight (swizzle algebra
// cancels: global chunk = ks*4+quad at row n, no XOR needed).
// Grid 1536, lid = (hw&7)*192 + hw>>3; mode: [0,512)K [512,1024)V [1024+)Q.
// ---------------------------------------------------------------------------
__global__ __launch_bounds__(256) void proj_kernel(
    const ushort* __restrict__ Qb, const ushort* __restrict__ Cb,
    const ushort* __restrict__ WTbase,
    const float* __restrict__ biasq, const float* __restrict__ biask,
    const float* __restrict__ biasv,
    ushort* __restrict__ Qw, ushort* __restrict__ Kw, ushort* __restrict__ Vtw,
    float scale)
{
    __shared__ ushort As[2][128 * 64];
    const int tid = threadIdx.x;
    const int w = tid >> 6, lane = tid & 63;
    const int ln = tid & 15, quad = (tid >> 4) & 3;
    const int wm = w >> 1, wn = w & 1;

    const int hw = blockIdx.x;
    const int lid = (hw & 7) * 192 + (hw >> 3);   // XCD-contiguous (1536=8*192)
    const int mode = lid >> 9;                    // 0=K, 1=V, 2=Q
    const int rem = lid & 511;
    const int m0 = (rem >> 3) * 128;
    const int n0 = (rem & 7) * 128;
    const ushort* Ag = (mode == 2) ? Qb : Cb;
    const ushort* BT = (mode == 2) ? WTbase : WTbase + (size_t)(1 + mode) * 1048576;

    int offA[4], lseg[4];
#pragma unroll
    for (int rr = 0; rr < 4; ++rr) {
        int idx2 = (rr * 4 + w) * 64 + lane;
        int r = idx2 >> 3, cst = idx2 & 7, csrc = cst ^ (r & 7);
        offA[rr] = (m0 + r) * 1024 + csrc * 8;
        lseg[rr] = (rr * 4 + w) * 512;
    }
    // per-wave B row base: rows n0+wn*64+j*16+ln, row-major [n][k]
    const ushort* Bp = BT + (size_t)(n0 + wn * 64 + ln) * 1024;

    f32x4 acc[4][4] = {};

    // prologue: stage A K-step 0 into buffer 0
#pragma unroll
    for (int rr = 0; rr < 4; ++rr)
        gll16(&Ag[(size_t)offA[rr]], &As[0][lseg[rr]]);
    __syncthreads();

    for (int kt = 0; kt < 16; ++kt) {
        const int cur = kt & 1;
        if (kt < 15) {
#pragma unroll
            for (int rr = 0; rr < 4; ++rr)
                gll16(&Ag[(size_t)(offA[rr] + (kt + 1) * 64)], &As[cur ^ 1][lseg[rr]]);
        }
        const ushort* Ac = As[cur];
#pragma unroll
        for (int ks = 0; ks < 2; ++ks) {
            short8 af[4], bfr[4];
#pragma unroll
            for (int i = 0; i < 4; ++i)
                af[i] = *(const short8*)&Ac[(wm * 64 + i * 16 + ln) * 64 +
                                            ((ks * 4 + quad) ^ (ln & 7)) * 8];
#pragma unroll
            for (int j = 0; j < 4; ++j)
                bfr[j] = *(const short8*)&Bp[(size_t)(j * 16) * 1024 +
                                             kt * 64 + (ks * 4 + quad) * 8];
#pragma unroll
            for (int i = 0; i < 4; ++i)
#pragma unroll
                for (int j = 0; j < 4; ++j)
                    acc[i][j] = MFMA16(af[i], bfr[j], acc[i][j]);
        }
        __syncthreads();
    }

    if (mode == 1) {
        // V: transposed store [b,h,d,t]
#pragma unroll
        for (int j = 0; j < 4; ++j) {
            int n = n0 + wn * 64 + j * 16 + ln;
            int h = n >> 6, d = n & 63;
            float bvv = biasv[n];
#pragma unroll
            for (int i = 0; i < 4; ++i) {
                int mb = m0 + wm * 64 + i * 16 + quad * 4;
                int b = mb >> 11, t = mb & 2047;
                pk4_u o;
                o.u2[0] = pk_bf16(acc[i][j][0] + bvv, acc[i][j][1] + bvv);
                o.u2[1] = pk_bf16(acc[i][j][2] + bvv, acc[i][j][3] + bvv);
                *(short4_t*)&Vtw[(((size_t)((b * 16 + h) * 64 + d)) << 11) + t] = o.s4;
            }
        }
    } else {
        ushort* Out = (mode == 2) ? Qw : Kw;
        const float* bias = (mode == 2) ? biasq : biask;
        float sc = (mode == 2) ? scale : 1.0f;
#pragma unroll
        for (int j = 0; j < 4; ++j) {
            int n = n0 + wn * 64 + j * 16 + ln;
            int h = n >> 6, d = n & 63;
            float bvv = bias[n];
#pragma unroll
            for (int i = 0; i < 4; ++i) {
                int mb = m0 + wm * 64 + i * 16 + quad * 4;
#pragma unroll
                for (int r = 0; r < 4; ++r) {
                    int m = mb + r, b = m >> 11, t = m & 2047;
                    Out[(((size_t)(b * 16 + h) * 2048 + t) << 6) + d] =
                        (ushort)f2b((acc[i][j][r] + bvv) * sc);
                }
            }
        }
    }
}

// ---------------------------------------------------------------------------
// Output projection GEMM v2: same A-dbuf + direct-B structure as proj.
// Grid 512, lid = (hw&7)*64 + hw>>3 (XCD-contiguous).
// ---------------------------------------------------------------------------
__global__ __launch_bounds__(256) void gemm_o_kernel(
    const ushort* __restrict__ Ag, const ushort* __restrict__ BT,
    const float* __restrict__ bias, float* __restrict__ Out)
{
    __shared__ ushort As[2][128 * 64];
    const int tid = threadIdx.x;
    const int w = tid >> 6, lane = tid & 63;
    const int ln = tid & 15, quad = (tid >> 4) & 3;
    const int wm = w >> 1, wn = w & 1;
    const int hw = blockIdx.x;
    const int lid = (hw & 7) * 64 + (hw >> 3);    // XCD-contiguous (512=8*64)
    const int m0 = (lid >> 3) * 128, n0 = (lid & 7) * 128;

    int offA[4], lseg[4];
#pragma unroll
    for (int rr = 0; rr < 4; ++rr) {
        int idx = (rr * 4 + w) * 64 + lane;
        int r = idx >> 3, cst = idx & 7, csrc = cst ^ (r & 7);
        offA[rr] = (m0 + r) * 1024 + csrc * 8;
        lseg[rr] = (rr * 4 + w) * 512;
    }
    const ushort* Bp = BT + (size_t)(n0 + wn * 64 + ln) * 1024;

    f32x4 acc[4][4] = {};

#pragma unroll
    for (int rr = 0; rr < 4; ++rr)
        gll16(&Ag[(size_t)offA[rr]], &As[0][lseg[rr]]);
    __syncthreads();

    for (int kt = 0; kt < 16; ++kt) {
        const int cur = kt & 1;
        if (kt < 15) {
#pragma unroll
            for (int rr = 0; rr < 4; ++rr)
                gll16(&Ag[(size_t)(offA[rr] + (kt + 1) * 64)], &As[cur ^ 1][lseg[rr]]);
        }
        const ushort* Ac = As[cur];
#pragma unroll
        for (int ks = 0; ks < 2; ++ks) {
            short8 af[4], bfr[4];
#pragma unroll
            for (int i = 0; i < 4; ++i)
                af[i] = *(const short8*)&Ac[(wm * 64 + i * 16 + ln) * 64 +
                                            ((ks * 4 + quad) ^ (ln & 7)) * 8];
#pragma unroll
            for (int j = 0; j < 4; ++j)
                bfr[j] = *(const short8*)&Bp[(size_t)(j * 16) * 1024 +
                                             kt * 64 + (ks * 4 + quad) * 8];
#pragma unroll
            for (int i = 0; i < 4; ++i)
#pragma unroll
                for (int j = 0; j < 4; ++j)
                    acc[i][j] = MFMA16(af[i], bfr[j], acc[i][j]);
        }
        __syncthreads();
    }

#pragma unroll
    for (int j = 0; j < 4; ++j) {
        int n = n0 + wn * 64 + j * 16 + ln;
        float bv = bias[n];
#pragma unroll
        for (int i = 0; i < 4; ++i) {
            int mb = m0 + wm * 64 + i * 16 + quad * 4;
#pragma unroll
            for (int r = 0; r < 4; ++r)
                Out[(size_t)(mb + r) * 1024 + n] = acc[i][j][r] + bv;
        }
    }
}

// ---------------------------------------------------------------------------
// Flash attention v9 (unchanged from R7; 76.8us).
// ---------------------------------------------------------------------------
__global__ __launch_bounds__(256, 4) void attn_kernel(
    const ushort* __restrict__ Qw, const ushort* __restrict__ Kw,
    const ushort* __restrict__ Vtw, ushort* __restrict__ attn)
{
    __shared__ ushort Ks[2][4096];      // 64 kv x 64 d, XOR chunk swizzle
    __shared__ ushort Vts[2][4096];     // 64 d  x 64 kv, XOR chunk swizzle

    const int tid = threadIdx.x;
    const int w = tid >> 6, lane = tid & 63;
    const int ln = tid & 15, quad = (tid >> 4) & 3;
    // XCD swizzle (bijective over 1024 = 8*128): xcd = id&7 = bh&7.
    const int id = blockIdx.x;
    const int qt = (id >> 3) & 15;
    const int bh = (id & 7) | ((id >> 7) << 3);
    const int b = bh >> 4, h = bh & 15;

    const ushort* Qg = Qw + (size_t)bh * 131072 + (size_t)qt * 8192;
    const ushort* Kg = Kw + (size_t)bh * 131072;
    const ushort* Vg = Vtw + (size_t)bh * 131072;

    // Q fragments (B-operand of K=32 QK): lane holds Q[q=w*32+qs*16+ln][d]
    short8 bq[2][2];
#pragma unroll
    for (int qs = 0; qs < 2; ++qs)
#pragma unroll
        for (int ks = 0; ks < 2; ++ks)
            bq[qs][ks] = *(const short8*)&Qg[(w * 32 + qs * 16 + ln) * 64 + ks * 32 + quad * 8];

    int offK[2], offV[2], lseg[2];
#pragma unroll
    for (int rr = 0; rr < 2; ++rr) {
        int idx = (rr * 4 + w) * 64 + lane;
        int r = idx >> 3, cst = idx & 7, csrc = cst ^ (r & 7);
        offK[rr] = r * 64 + csrc * 8;
        offV[rr] = r * 2048 + csrc * 8;
        lseg[rr] = (rr * 4 + w) * 512;
    }

    const short8 ones8 = {(short)0x3F80, (short)0x3F80, (short)0x3F80, (short)0x3F80,
                          (short)0x3F80, (short)0x3F80, (short)0x3F80, (short)0x3F80};

    f32x4 Of[2][4] = {};     // O^T: col = q = ln (qs slab), rows = d-local quad*4+r
    f32x4 lac[2] = {};       // col-sums of P: col = q = ln, rows all equal

    // prologue: stage tile 0 into buffer 0 (drained by the barrier below)
#pragma unroll
    for (int rr = 0; rr < 2; ++rr) gll16(&Kg[offK[rr]], &Ks[0][lseg[rr]]);
#pragma unroll
    for (int rr = 0; rr < 2; ++rr) gll16(&Vg[offV[rr]], &Vts[0][lseg[rr]]);
    __syncthreads();

    auto body = [&](int kt, const ushort* Kc, const ushort* Vc,
                    ushort* Kn, ushort* Vn) {
        // issue next tile's async global->LDS loads FIRST; the end-of-body
        // barrier's vmcnt(0) drain then overlaps this tile's compute.
        if (kt < 31) {
#pragma unroll
            for (int rr = 0; rr < 2; ++rr)
                gll16(&Kg[(kt + 1) * 4096 + offK[rr]], &Kn[lseg[rr]]);
#pragma unroll
            for (int rr = 0; rr < 2; ++rr)
                gll16(&Vg[(kt + 1) * 64 + offV[rr]], &Vn[lseg[rr]]);
        }

#pragma unroll
        for (int c = 0; c < 2; ++c) {
            // batch K fragment reads, then a pure-MFMA QK cluster
            short8 a0[2], a1[2];
#pragma unroll
            for (int kb = 0; kb < 2; ++kb) {
                int kv = 2 * c + kb;
                a0[kb] = *(const short8*)&Kc[(kv * 16 + ln) * 64 + (quad ^ (ln & 7)) * 8];
                a1[kb] = *(const short8*)&Kc[(kv * 16 + ln) * 64 + ((4 + quad) ^ (ln & 7)) * 8];
            }
            f32x4 s[2][2];
            __builtin_amdgcn_s_setprio(1);
#pragma unroll
            for (int kb = 0; kb < 2; ++kb)
#pragma unroll
                for (int qs = 0; qs < 2; ++qs) {
                    f32x4 t = {};
                    t = MFMA16(a0[kb], bq[qs][0], t);
                    t = MFMA16(a1[kb], bq[qs][1], t);
                    s[kb][qs] = t;
                }
            __builtin_amdgcn_s_setprio(0);

            // exp2 + hardware pack into CONCATENATED K=32 B-operand
            short8 pf8[2];
#pragma unroll
            for (int qs = 0; qs < 2; ++qs) {
                pk8_u pu;
                pu.u4[0] = pk_bf16(__builtin_amdgcn_exp2f(s[0][qs][0]),
                                   __builtin_amdgcn_exp2f(s[0][qs][1]));
                pu.u4[1] = pk_bf16(__builtin_amdgcn_exp2f(s[0][qs][2]),
                                   __builtin_amdgcn_exp2f(s[0][qs][3]));
                pu.u4[2] = pk_bf16(__builtin_amdgcn_exp2f(s[1][qs][0]),
                                   __builtin_amdgcn_exp2f(s[1][qs][1]));
                pu.u4[3] = pk_bf16(__builtin_amdgcn_exp2f(s[1][qs][2]),
                                   __builtin_amdgcn_exp2f(s[1][qs][3]));
                pf8[qs] = pu.s8;
                lac[qs] = MFMA16(ones8, pu.s8, lac[qs]);   // denominator, K=32
            }

            // batch V fragment reads, then a pure-MFMA PV cluster
            cat8_u av[4];
#pragma unroll
            for (int ds = 0; ds < 4; ++ds) {
                const ushort* vrow = &Vc[(ds * 16 + ln) * 64];
                av[ds].s4[0] = *(const short4_t*)&vrow[(((4 * c + (quad >> 1)) ^ (ln & 7)) * 8) + (quad & 1) * 4];
                av[ds].s4[1] = *(const short4_t*)&vrow[(((4 * c + 2 + (quad >> 1)) ^ (ln & 7)) * 8) + (quad & 1) * 4];
            }
            __builtin_amdgcn_s_setprio(1);
#pragma unroll
            for (int ds = 0; ds < 4; ++ds)
#pragma unroll
                for (int qs = 0; qs < 2; ++qs)
                    Of[qs][ds] = MFMA16(av[ds].s8, pf8[qs], Of[qs][ds]);
            __builtin_amdgcn_s_setprio(0);
        }

        // single barrier per tile: drains next-tile vmcnt (overlapped with the
        // compute above) AND guarantees all waves finished reading this buffer.
        __syncthreads();
    };

    for (int kt = 0; kt < 32; kt += 2) {
        body(kt,     Ks[0], Vts[0], Ks[1], Vts[1]);
        body(kt + 1, Ks[1], Vts[1], Ks[0], Vts[0]);
    }

    // finalize: lane ln owns q = w*32 + qs*16 + ln for both l and O columns
#pragma unroll
    for (int qs = 0; qs < 2; ++qs) {
        float inv = __builtin_amdgcn_rcpf(lac[qs][0]);
        int t = qt * 128 + w * 32 + qs * 16 + ln;
        size_t base = ((size_t)(b * 2048 + t) << 10) + h * 64;
#pragma unroll
        for (int ds = 0; ds < 4; ++ds) {
            uint2 o;
            o.x = pk_bf16(Of[qs][ds][0] * inv, Of[qs][ds][1] * inv);
            o.y = pk_bf16(Of[qs][ds][2] * inv, Of[qs][ds][3] * inv);
            *(uint2*)&attn[base + ds * 16 + quad * 4] = o;
        }
    }
}

// ---------------------------------------------------------------------------
extern "C" void kernel_launch(void* const* d_in, const int* in_sizes, int n_in,
                              void* d_out, int out_size, void* d_ws, size_t ws_size,
                              hipStream_t stream)
{
    const float* query   = (const float*)d_in[0];
    const float* context = (const float*)d_in[1];
    const float* Wq = (const float*)d_in[2];
    const float* bq = (const float*)d_in[3];
    const float* Wk = (const float*)d_in[4];
    const float* bk = (const float*)d_in[5];
    const float* Wv = (const float*)d_in[6];
    const float* bv = (const float*)d_in[7];
    const float* Wo = (const float*)d_in[8];
    const float* bo = (const float*)d_in[9];

    char* ws = (char*)d_ws;
    ushort* WT  = (ushort*)ws;                        // 4 x 2 MB bf16 [n][k]
    ushort* Qb  = (ushort*)(ws + 8388608);            // query bf16; later Aw
    ushort* Qw  = (ushort*)(ws + 25165824);           // [b,h,t,d] (pre-scaled)
    ushort* Kw  = (ushort*)(ws + 41943040);           // [b,h,t,d]
    ushort* Vtw = (ushort*)(ws + 58720256);           // [b,h,d,t]
    ushort* Aw  = Qb;                                 // attn out reuses Qb
    ushort* Cb  = (ushort*)d_out;                     // context bf16 in d_out

    const float SCALE = 0.18033688011112042f;         // log2(e)/sqrt(64)

    cvt_all_kernel<<<dim3(9216), 256, 0, stream>>>(query, context, Qb, Cb,
                                                   Wq, Wk, Wv, Wo, WT);
    proj_kernel<<<dim3(1536), 256, 0, stream>>>(Qb, Cb, WT, bq, bk, bv,
                                                Qw, Kw, Vtw, SCALE);
    attn_kernel<<<dim3(1024), 256, 0, stream>>>(Qw, Kw, Vtw, Aw);
    gemm_o_kernel<<<dim3(512), 256, 0, stream>>>(Aw, WT + 3 * 1048576, bo,
                                                 (float*)d_out);
}

// Round 10
// 325.452 us; speedup vs baseline: 1.0747x; 1.0747x over previous
//
#include <hip/hip_runtime.h>
#include <hip/hip_bf16.h>
#include <cstdint>

typedef __attribute__((ext_vector_type(8))) short short8;
typedef __attribute__((ext_vector_type(4))) short short4_t;
typedef __attribute__((ext_vector_type(4))) float f32x4;

#define MFMA16(a, b, c) __builtin_amdgcn_mfma_f32_16x16x32_bf16(a, b, c, 0, 0, 0)

__device__ __forceinline__ short f2b(float f) {
    union { float fp; unsigned u; } un; un.fp = f;
    unsigned r = un.u + 0x7fffu + ((un.u >> 16) & 1u);
    return (short)(r >> 16);
}

// gfx950 has NO __builtin_amdgcn_cvt_pk_bf16_f32 (learn_hip m240); use the
// HW instruction directly. RNE rounding == f2b. dst.lo=cvt(a), dst.hi=cvt(b).
__device__ __forceinline__ unsigned pk_bf16(float a, float b) {
    unsigned r;
    asm("v_cvt_pk_bf16_f32 %0, %1, %2" : "=v"(r) : "v"(a), "v"(b));
    return r;
}

union pk8_u { unsigned u4[4]; short8 s8; };
union pk4_u { unsigned u2[2]; short4_t s4; };
union cat8_u { short4_t s4[2]; short8 s8; };

typedef const __attribute__((address_space(1))) unsigned g_as1;
typedef __attribute__((address_space(3))) unsigned l_as3;
__device__ __forceinline__ void gll16(const ushort* g, ushort* l) {
    __builtin_amdgcn_global_load_lds((g_as1*)g, (l_as3*)l, 16, 0, 0);
}

// ---------------------------------------------------------------------------
// Merged converts (one launch): ids [0,8192) = fp32->bf16 of query/context,
// ids [8192,9216) = weight transpose+convert fp32 [k][n] -> bf16 [n][k].
// ---------------------------------------------------------------------------
__global__ __launch_bounds__(256) void cvt_all_kernel(
    const float* __restrict__ q, const float* __restrict__ c,
    ushort* __restrict__ qb, ushort* __restrict__ cb,
    const float* __restrict__ Wq, const float* __restrict__ Wk,
    const float* __restrict__ Wv, const float* __restrict__ Wo,
    ushort* __restrict__ wt)
{
    __shared__ float Ts[64 * 65];
    const int id = blockIdx.x;
    const int tid = threadIdx.x;

    if (id < 8192) {
        const float* src = (id >= 4096) ? c : q;
        ushort* dst = (id >= 4096) ? cb : qb;
        size_t i = ((size_t)(id & 4095) * 256 + tid) * 8;
        float4 v0 = *(const float4*)&src[i];
        float4 v1 = *(const float4*)&src[i + 4];
        uint4 o;
        o.x = pk_bf16(v0.x, v0.y); o.y = pk_bf16(v0.z, v0.w);
        o.z = pk_bf16(v1.x, v1.y); o.w = pk_bf16(v1.z, v1.w);
        *(uint4*)&dst[i] = o;
        return;
    }

    const int u = id - 8192;
    const int z = u >> 8;
    const float* W = (z == 0) ? Wq : (z == 1) ? Wk : (z == 2) ? Wv : Wo;
    ushort* WT = wt + (size_t)z * (1024 * 1024);
    const int n0 = (u & 15) * 64, k0 = ((u >> 4) & 15) * 64;

#pragma unroll
    for (int rr = 0; rr < 4; ++rr) {
        int uu = tid + rr * 256;
        int r = uu >> 4, cc = (uu & 15) * 4;
        float4 v = *(const float4*)&W[(size_t)(k0 + r) * 1024 + n0 + cc];
        Ts[r * 65 + cc + 0] = v.x; Ts[r * 65 + cc + 1] = v.y;
        Ts[r * 65 + cc + 2] = v.z; Ts[r * 65 + cc + 3] = v.w;
    }
    __syncthreads();
#pragma unroll
    for (int rr = 0; rr < 4; ++rr) {
        int uu = tid + rr * 256;
        int rn = uu >> 4, ck = (uu & 15) * 4;
        pk4_u o;
        o.u2[0] = pk_bf16(Ts[(ck + 0) * 65 + rn], Ts[(ck + 1) * 65 + rn]);
        o.u2[1] = pk_bf16(Ts[(ck + 2) * 65 + rn], Ts[(ck + 3) * 65 + rn]);
        *(short4_t*)&WT[(size_t)(n0 + rn) * 1024 + k0 + ck] = o.s4;
    }
}

// ---------------------------------------------------------------------------
// Q/K/V projection v4: BK=32, BOTH operands double-buffered in 32KB LDS
// (4x8KB, same footprint as R7 -> 4-5 blk/CU kept), ONE barrier per K-step
// with next-step prefetch issued before compute (attn's proven pattern;
// kills R7's naked per-step vmcnt(0) drain). R8 lesson: never exceed 32KB.
// R9 lesson: never put L2 loads on the immediate MFMA path.
// LDS unit layout (conflict-free at 32-wide rows): unit u <-> (row r, chunk c)
//   r = (u>>3)*2 + (u&1), c = (u>>1)&3, source chunk csrc = c ^ ((r>>1)&3).
// Fragment read offset (base rows are multiples of 16):
//   off(row_blk i) = (wm*32 + i*8 + (ln>>1))*64 + (quad^((ln>>1)&3))*16 + (ln&1)*8
// -> 16 lanes hit all 32 banks (2-way = free, m136).
// Grid 1536, lid = (hw&7)*192 + hw>>3; mode: [0,512)K [512,1024)V [1024+)Q.
// ---------------------------------------------------------------------------
__global__ __launch_bounds__(256) void proj_kernel(
    const ushort* __restrict__ Qb, const ushort* __restrict__ Cb,
    const ushort* __restrict__ WTbase,
    const float* __restrict__ biasq, const float* __restrict__ biask,
    const float* __restrict__ biasv,
    ushort* __restrict__ Qw, ushort* __restrict__ Kw, ushort* __restrict__ Vtw,
    float scale)
{
    __shared__ ushort As[2][128 * 32];
    __shared__ ushort Bs[2][128 * 32];
    const int tid = threadIdx.x;
    const int w = tid >> 6;
    const int ln = tid & 15, quad = (tid >> 4) & 3;
    const int wm = w >> 1, wn = w & 1;

    const int hw = blockIdx.x;
    const int lid = (hw & 7) * 192 + (hw >> 3);   // XCD-contiguous (1536=8*192)
    const int mode = lid >> 9;                    // 0=K, 1=V, 2=Q
    const int rem = lid & 511;
    const int m0 = (rem >> 3) * 128;
    const int n0 = (rem & 7) * 128;
    const ushort* Ag = (mode == 2) ? Qb : Cb;
    const ushort* BT = (mode == 2) ? WTbase : WTbase + (size_t)(1 + mode) * 1048576;

    // staging addresses: 2 rounds x 256 threads x 16B = 8KB per matrix
    int offA[2], offB[2], lbase[2];
#pragma unroll
    for (int rnd = 0; rnd < 2; ++rnd) {
        int u = rnd * 256 + tid;
        int r = ((u >> 3) << 1) | (u & 1);
        int c = (u >> 1) & 3;
        int csrc = c ^ ((u >> 3) & 3);
        offA[rnd] = (m0 + r) * 1024 + csrc * 8;
        offB[rnd] = (n0 + r) * 1024 + csrc * 8;
        lbase[rnd] = rnd * 2048 + w * 512;        // wave-uniform LDS base
    }
    // fragment read bases
    const int acol = (quad ^ ((ln >> 1) & 3)) * 16 + (ln & 1) * 8;
    const int arow = wm * 32 + (ln >> 1);
    const int brow = wn * 32 + (ln >> 1);

    f32x4 acc[4][4] = {};

    // prologue: stage K-step 0 into buffer 0
#pragma unroll
    for (int rnd = 0; rnd < 2; ++rnd) {
        gll16(&Ag[(size_t)offA[rnd]], &As[0][lbase[rnd]]);
        gll16(&BT[(size_t)offB[rnd]], &Bs[0][lbase[rnd]]);
    }
    __syncthreads();

    for (int kt = 0; kt < 32; ++kt) {
        const int cur = kt & 1;
        if (kt < 31) {
#pragma unroll
            for (int rnd = 0; rnd < 2; ++rnd) {
                gll16(&Ag[(size_t)(offA[rnd] + (kt + 1) * 32)], &As[cur ^ 1][lbase[rnd]]);
                gll16(&BT[(size_t)(offB[rnd] + (kt + 1) * 32)], &Bs[cur ^ 1][lbase[rnd]]);
            }
        }
        const ushort* Ac = As[cur];
        const ushort* Bc = Bs[cur];
        short8 af[4], bfr[4];
#pragma unroll
        for (int i = 0; i < 4; ++i)
            af[i] = *(const short8*)&Ac[(arow + i * 8) * 64 + acol];
#pragma unroll
        for (int j = 0; j < 4; ++j)
            bfr[j] = *(const short8*)&Bc[(brow + j * 8) * 64 + acol];
#pragma unroll
        for (int i = 0; i < 4; ++i)
#pragma unroll
            for (int j = 0; j < 4; ++j)
                acc[i][j] = MFMA16(af[i], bfr[j], acc[i][j]);
        // single barrier per step: drains next-step vmcnt (overlapped with
        // the compute above) AND protects buffer cur from early overwrite.
        __syncthreads();
    }

    if (mode == 1) {
        // V: transposed store [b,h,d,t]
#pragma unroll
        for (int j = 0; j < 4; ++j) {
            int n = n0 + wn * 64 + j * 16 + ln;
            int h = n >> 6, d = n & 63;
            float bvv = biasv[n];
#pragma unroll
            for (int i = 0; i < 4; ++i) {
                int mb = m0 + wm * 64 + i * 16 + quad * 4;
                int b = mb >> 11, t = mb & 2047;
                pk4_u o;
                o.u2[0] = pk_bf16(acc[i][j][0] + bvv, acc[i][j][1] + bvv);
                o.u2[1] = pk_bf16(acc[i][j][2] + bvv, acc[i][j][3] + bvv);
                *(short4_t*)&Vtw[(((size_t)((b * 16 + h) * 64 + d)) << 11) + t] = o.s4;
            }
        }
    } else {
        ushort* Out = (mode == 2) ? Qw : Kw;
        const float* bias = (mode == 2) ? biasq : biask;
        float sc = (mode == 2) ? scale : 1.0f;
#pragma unroll
        for (int j = 0; j < 4; ++j) {
            int n = n0 + wn * 64 + j * 16 + ln;
            int h = n >> 6, d = n & 63;
            float bvv = bias[n];
#pragma unroll
            for (int i = 0; i < 4; ++i) {
                int mb = m0 + wm * 64 + i * 16 + quad * 4;
#pragma unroll
                for (int r = 0; r < 4; ++r) {
                    int m = mb + r, b = m >> 11, t = m & 2047;
                    Out[(((size_t)(b * 16 + h) * 2048 + t) << 6) + d] =
                        (ushort)f2b((acc[i][j][r] + bvv) * sc);
                }
            }
        }
    }
}

// ---------------------------------------------------------------------------
// Output projection GEMM v3: same BK=32 dbuf one-barrier structure as proj.
// Grid 512, lid = (hw&7)*64 + hw>>3 (XCD-contiguous). fp32 row-major out.
// ---------------------------------------------------------------------------
__global__ __launch_bounds__(256) void gemm_o_kernel(
    const ushort* __restrict__ Ag, const ushort* __restrict__ BT,
    const float* __restrict__ bias, float* __restrict__ Out)
{
    __shared__ ushort As[2][128 * 32];
    __shared__ ushort Bs[2][128 * 32];
    const int tid = threadIdx.x;
    const int w = tid >> 6;
    const int ln = tid & 15, quad = (tid >> 4) & 3;
    const int wm = w >> 1, wn = w & 1;
    const int hw = blockIdx.x;
    const int lid = (hw & 7) * 64 + (hw >> 3);    // XCD-contiguous (512=8*64)
    const int m0 = (lid >> 3) * 128, n0 = (lid & 7) * 128;

    int offA[2], offB[2], lbase[2];
#pragma unroll
    for (int rnd = 0; rnd < 2; ++rnd) {
        int u = rnd * 256 + tid;
        int r = ((u >> 3) << 1) | (u & 1);
        int c = (u >> 1) & 3;
        int csrc = c ^ ((u >> 3) & 3);
        offA[rnd] = (m0 + r) * 1024 + csrc * 8;
        offB[rnd] = (n0 + r) * 1024 + csrc * 8;
        lbase[rnd] = rnd * 2048 + w * 512;
    }
    const int acol = (quad ^ ((ln >> 1) & 3)) * 16 + (ln & 1) * 8;
    const int arow = wm * 32 + (ln >> 1);
    const int brow = wn * 32 + (ln >> 1);

    f32x4 acc[4][4] = {};

#pragma unroll
    for (int rnd = 0; rnd < 2; ++rnd) {
        gll16(&Ag[(size_t)offA[rnd]], &As[0][lbase[rnd]]);
        gll16(&BT[(size_t)offB[rnd]], &Bs[0][lbase[rnd]]);
    }
    __syncthreads();

    for (int kt = 0; kt < 32; ++kt) {
        const int cur = kt & 1;
        if (kt < 31) {
#pragma unroll
            for (int rnd = 0; rnd < 2; ++rnd) {
                gll16(&Ag[(size_t)(offA[rnd] + (kt + 1) * 32)], &As[cur ^ 1][lbase[rnd]]);
                gll16(&BT[(size_t)(offB[rnd] + (kt + 1) * 32)], &Bs[cur ^ 1][lbase[rnd]]);
            }
        }
        const ushort* Ac = As[cur];
        const ushort* Bc = Bs[cur];
        short8 af[4], bfr[4];
#pragma unroll
        for (int i = 0; i < 4; ++i)
            af[i] = *(const short8*)&Ac[(arow + i * 8) * 64 + acol];
#pragma unroll
        for (int j = 0; j < 4; ++j)
            bfr[j] = *(const short8*)&Bc[(brow + j * 8) * 64 + acol];
#pragma unroll
        for (int i = 0; i < 4; ++i)
#pragma unroll
            for (int j = 0; j < 4; ++j)
                acc[i][j] = MFMA16(af[i], bfr[j], acc[i][j]);
        __syncthreads();
    }

#pragma unroll
    for (int j = 0; j < 4; ++j) {
        int n = n0 + wn * 64 + j * 16 + ln;
        float bv = bias[n];
#pragma unroll
        for (int i = 0; i < 4; ++i) {
            int mb = m0 + wm * 64 + i * 16 + quad * 4;
#pragma unroll
            for (int r = 0; r < 4; ++r)
                Out[(size_t)(mb + r) * 1024 + n] = acc[i][j][r] + bv;
        }
    }
}

// ---------------------------------------------------------------------------
// Flash attention v9 (unchanged from R7; 76.8us).
// ---------------------------------------------------------------------------
__global__ __launch_bounds__(256, 4) void attn_kernel(
    const ushort* __restrict__ Qw, const ushort* __restrict__ Kw,
    const ushort* __restrict__ Vtw, ushort* __restrict__ attn)
{
    __shared__ ushort Ks[2][4096];      // 64 kv x 64 d, XOR chunk swizzle
    __shared__ ushort Vts[2][4096];     // 64 d  x 64 kv, XOR chunk swizzle

    const int tid = threadIdx.x;
    const int w = tid >> 6, lane = tid & 63;
    const int ln = tid & 15, quad = (tid >> 4) & 3;
    // XCD swizzle (bijective over 1024 = 8*128): xcd = id&7 = bh&7.
    const int id = blockIdx.x;
    const int qt = (id >> 3) & 15;
    const int bh = (id & 7) | ((id >> 7) << 3);
    const int b = bh >> 4, h = bh & 15;

    const ushort* Qg = Qw + (size_t)bh * 131072 + (size_t)qt * 8192;
    const ushort* Kg = Kw + (size_t)bh * 131072;
    const ushort* Vg = Vtw + (size_t)bh * 131072;

    // Q fragments (B-operand of K=32 QK): lane holds Q[q=w*32+qs*16+ln][d]
    short8 bq[2][2];
#pragma unroll
    for (int qs = 0; qs < 2; ++qs)
#pragma unroll
        for (int ks = 0; ks < 2; ++ks)
            bq[qs][ks] = *(const short8*)&Qg[(w * 32 + qs * 16 + ln) * 64 + ks * 32 + quad * 8];

    int offK[2], offV[2], lseg[2];
#pragma unroll
    for (int rr = 0; rr < 2; ++rr) {
        int idx = (rr * 4 + w) * 64 + lane;
        int r = idx >> 3, cst = idx & 7, csrc = cst ^ (r & 7);
        offK[rr] = r * 64 + csrc * 8;
        offV[rr] = r * 2048 + csrc * 8;
        lseg[rr] = (rr * 4 + w) * 512;
    }

    const short8 ones8 = {(short)0x3F80, (short)0x3F80, (short)0x3F80, (short)0x3F80,
                          (short)0x3F80, (short)0x3F80, (short)0x3F80, (short)0x3F80};

    f32x4 Of[2][4] = {};     // O^T: col = q = ln (qs slab), rows = d-local quad*4+r
    f32x4 lac[2] = {};       // col-sums of P: col = q = ln, rows all equal

    // prologue: stage tile 0 into buffer 0 (drained by the barrier below)
#pragma unroll
    for (int rr = 0; rr < 2; ++rr) gll16(&Kg[offK[rr]], &Ks[0][lseg[rr]]);
#pragma unroll
    for (int rr = 0; rr < 2; ++rr) gll16(&Vg[offV[rr]], &Vts[0][lseg[rr]]);
    __syncthreads();

    auto body = [&](int kt, const ushort* Kc, const ushort* Vc,
                    ushort* Kn, ushort* Vn) {
        // issue next tile's async global->LDS loads FIRST; the end-of-body
        // barrier's vmcnt(0) drain then overlaps this tile's compute.
        if (kt < 31) {
#pragma unroll
            for (int rr = 0; rr < 2; ++rr)
                gll16(&Kg[(kt + 1) * 4096 + offK[rr]], &Kn[lseg[rr]]);
#pragma unroll
            for (int rr = 0; rr < 2; ++rr)
                gll16(&Vg[(kt + 1) * 64 + offV[rr]], &Vn[lseg[rr]]);
        }

#pragma unroll
        for (int c = 0; c < 2; ++c) {
            // batch K fragment reads, then a pure-MFMA QK cluster
            short8 a0[2], a1[2];
#pragma unroll
            for (int kb = 0; kb < 2; ++kb) {
                int kv = 2 * c + kb;
                a0[kb] = *(const short8*)&Kc[(kv * 16 + ln) * 64 + (quad ^ (ln & 7)) * 8];
                a1[kb] = *(const short8*)&Kc[(kv * 16 + ln) * 64 + ((4 + quad) ^ (ln & 7)) * 8];
            }
            f32x4 s[2][2];
            __builtin_amdgcn_s_setprio(1);
#pragma unroll
            for (int kb = 0; kb < 2; ++kb)
#pragma unroll
                for (int qs = 0; qs < 2; ++qs) {
                    f32x4 t = {};
                    t = MFMA16(a0[kb], bq[qs][0], t);
                    t = MFMA16(a1[kb], bq[qs][1], t);
                    s[kb][qs] = t;
                }
            __builtin_amdgcn_s_setprio(0);

            // exp2 + hardware pack into CONCATENATED K=32 B-operand
            short8 pf8[2];
#pragma unroll
            for (int qs = 0; qs < 2; ++qs) {
                pk8_u pu;
                pu.u4[0] = pk_bf16(__builtin_amdgcn_exp2f(s[0][qs][0]),
                                   __builtin_amdgcn_exp2f(s[0][qs][1]));
                pu.u4[1] = pk_bf16(__builtin_amdgcn_exp2f(s[0][qs][2]),
                                   __builtin_amdgcn_exp2f(s[0][qs][3]));
                pu.u4[2] = pk_bf16(__builtin_amdgcn_exp2f(s[1][qs][0]),
                                   __builtin_amdgcn_exp2f(s[1][qs][1]));
                pu.u4[3] = pk_bf16(__builtin_amdgcn_exp2f(s[1][qs][2]),
                                   __builtin_amdgcn_exp2f(s[1][qs][3]));
                pf8[qs] = pu.s8;
                lac[qs] = MFMA16(ones8, pu.s8, lac[qs]);   // denominator, K=32
            }

            // batch V fragment reads, then a pure-MFMA PV cluster
            cat8_u av[4];
#pragma unroll
            for (int ds = 0; ds < 4; ++ds) {
                const ushort* vrow = &Vc[(ds * 16 + ln) * 64];
                av[ds].s4[0] = *(const short4_t*)&vrow[(((4 * c + (quad >> 1)) ^ (ln & 7)) * 8) + (quad & 1) * 4];
                av[ds].s4[1] = *(const short4_t*)&vrow[(((4 * c + 2 + (quad >> 1)) ^ (ln & 7)) * 8) + (quad & 1) * 4];
            }
            __builtin_amdgcn_s_setprio(1);
#pragma unroll
            for (int ds = 0; ds < 4; ++ds)
#pragma unroll
                for (int qs = 0; qs < 2; ++qs)
                    Of[qs][ds] = MFMA16(av[ds].s8, pf8[qs], Of[qs][ds]);
            __builtin_amdgcn_s_setprio(0);
        }

        // single barrier per tile: drains next-tile vmcnt (overlapped with the
        // compute above) AND guarantees all waves finished reading this buffer.
        __syncthreads();
    };

    for (int kt = 0; kt < 32; kt += 2) {
        body(kt,     Ks[0], Vts[0], Ks[1], Vts[1]);
        body(kt + 1, Ks[1], Vts[1], Ks[0], Vts[0]);
    }

    // finalize: lane ln owns q = w*32 + qs*16 + ln for both l and O columns
#pragma unroll
    for (int qs = 0; qs < 2; ++qs) {
        float inv = __builtin_amdgcn_rcpf(lac[qs][0]);
        int t = qt * 128 + w * 32 + qs * 16 + ln;
        size_t base = ((size_t)(b * 2048 + t) << 10) + h * 64;
#pragma unroll
        for (int ds = 0; ds < 4; ++ds) {
            uint2 o;
            o.x = pk_bf16(Of[qs][ds][0] * inv, Of[qs][ds][1] * inv);
            o.y = pk_bf16(Of[qs][ds][2] * inv, Of[qs][ds][3] * inv);
            *(uint2*)&attn[base + ds * 16 + quad * 4] = o;
        }
    }
}

// ---------------------------------------------------------------------------
extern "C" void kernel_launch(void* const* d_in, const int* in_sizes, int n_in,
                              void* d_out, int out_size, void* d_ws, size_t ws_size,
                              hipStream_t stream)
{
    const float* query   = (const float*)d_in[0];
    const float* context = (const float*)d_in[1];
    const float* Wq = (const float*)d_in[2];
    const float* bq = (const float*)d_in[3];
    const float* Wk = (const float*)d_in[4];
    const float* bk = (const float*)d_in[5];
    const float* Wv = (const float*)d_in[6];
    const float* bv = (const float*)d_in[7];
    const float* Wo = (const float*)d_in[8];
    const float* bo = (const float*)d_in[9];

    char* ws = (char*)d_ws;
    ushort* WT  = (ushort*)ws;                        // 4 x 2 MB bf16 [n][k]
    ushort* Qb  = (ushort*)(ws + 8388608);            // query bf16; later Aw
    ushort* Qw  = (ushort*)(ws + 25165824);           // [b,h,t,d] (pre-scaled)
    ushort* Kw  = (ushort*)(ws + 41943040);           // [b,h,t,d]
    ushort* Vtw = (ushort*)(ws + 58720256);           // [b,h,d,t]
    ushort* Aw  = Qb;                                 // attn out reuses Qb
    ushort* Cb  = (ushort*)d_out;                     // context bf16 in d_out

    const float SCALE = 0.18033688011112042f;         // log2(e)/sqrt(64)

    cvt_all_kernel<<<dim3(9216), 256, 0, stream>>>(query, context, Qb, Cb,
                                                   Wq, Wk, Wv, Wo, WT);
    proj_kernel<<<dim3(1536), 256, 0, stream>>>(Qb, Cb, WT, bq, bk, bv,
                                                Qw, Kw, Vtw, SCALE);
    attn_kernel<<<dim3(1024), 256, 0, stream>>>(Qw, Kw, Vtw, Aw);
    gemm_o_kernel<<<dim3(512), 256, 0, stream>>>(Aw, WT + 3 * 1048576, bo,
                                                 (float*)d_out);
}

// Round 11
// 291.727 us; speedup vs baseline: 1.1990x; 1.1156x over previous
//
#include <hip/hip_runtime.h>
#include <hip/hip_bf16.h>
#include <cstdint>

typedef __attribute__((ext_vector_type(8))) short short8;
typedef __attribute__((ext_vector_type(4))) short short4_t;
typedef __attribute__((ext_vector_type(4))) float f32x4;

#define MFMA16(a, b, c) __builtin_amdgcn_mfma_f32_16x16x32_bf16(a, b, c, 0, 0, 0)

__device__ __forceinline__ short f2b(float f) {
    union { float fp; unsigned u; } un; un.fp = f;
    unsigned r = un.u + 0x7fffu + ((un.u >> 16) & 1u);
    return (short)(r >> 16);
}

// gfx950 has NO __builtin_amdgcn_cvt_pk_bf16_f32 (learn_hip m240); use the
// HW instruction directly. RNE rounding == f2b. dst.lo=cvt(a), dst.hi=cvt(b).
__device__ __forceinline__ unsigned pk_bf16(float a, float b) {
    unsigned r;
    asm("v_cvt_pk_bf16_f32 %0, %1, %2" : "=v"(r) : "v"(a), "v"(b));
    return r;
}

union pk8_u { unsigned u4[4]; short8 s8; };
union pk4_u { unsigned u2[2]; short4_t s4; };
union cat8_u { short4_t s4[2]; short8 s8; };

typedef const __attribute__((address_space(1))) unsigned g_as1;
typedef __attribute__((address_space(3))) unsigned l_as3;
__device__ __forceinline__ void gll16(const ushort* g, ushort* l) {
    __builtin_amdgcn_global_load_lds((g_as1*)g, (l_as3*)l, 16, 0, 0);
}

// ---------------------------------------------------------------------------
// Merged converts (one launch): ids [0,8192) = fp32->bf16 of query/context,
// ids [8192,9216) = weight transpose+convert fp32 [k][n] -> bf16 [n][k].
// ---------------------------------------------------------------------------
__global__ __launch_bounds__(256) void cvt_all_kernel(
    const float* __restrict__ q, const float* __restrict__ c,
    ushort* __restrict__ qb, ushort* __restrict__ cb,
    const float* __restrict__ Wq, const float* __restrict__ Wk,
    const float* __restrict__ Wv, const float* __restrict__ Wo,
    ushort* __restrict__ wt)
{
    __shared__ float Ts[64 * 65];
    const int id = blockIdx.x;
    const int tid = threadIdx.x;

    if (id < 8192) {
        const float* src = (id >= 4096) ? c : q;
        ushort* dst = (id >= 4096) ? cb : qb;
        size_t i = ((size_t)(id & 4095) * 256 + tid) * 8;
        float4 v0 = *(const float4*)&src[i];
        float4 v1 = *(const float4*)&src[i + 4];
        uint4 o;
        o.x = pk_bf16(v0.x, v0.y); o.y = pk_bf16(v0.z, v0.w);
        o.z = pk_bf16(v1.x, v1.y); o.w = pk_bf16(v1.z, v1.w);
        *(uint4*)&dst[i] = o;
        return;
    }

    const int u = id - 8192;
    const int z = u >> 8;
    const float* W = (z == 0) ? Wq : (z == 1) ? Wk : (z == 2) ? Wv : Wo;
    ushort* WT = wt + (size_t)z * (1024 * 1024);
    const int n0 = (u & 15) * 64, k0 = ((u >> 4) & 15) * 64;

#pragma unroll
    for (int rr = 0; rr < 4; ++rr) {
        int uu = tid + rr * 256;
        int r = uu >> 4, cc = (uu & 15) * 4;
        float4 v = *(const float4*)&W[(size_t)(k0 + r) * 1024 + n0 + cc];
        Ts[r * 65 + cc + 0] = v.x; Ts[r * 65 + cc + 1] = v.y;
        Ts[r * 65 + cc + 2] = v.z; Ts[r * 65 + cc + 3] = v.w;
    }
    __syncthreads();
#pragma unroll
    for (int rr = 0; rr < 4; ++rr) {
        int uu = tid + rr * 256;
        int rn = uu >> 4, ck = (uu & 15) * 4;
        pk4_u o;
        o.u2[0] = pk_bf16(Ts[(ck + 0) * 65 + rn], Ts[(ck + 1) * 65 + rn]);
        o.u2[1] = pk_bf16(Ts[(ck + 2) * 65 + rn], Ts[(ck + 3) * 65 + rn]);
        *(short4_t*)&WT[(size_t)(n0 + rn) * 1024 + k0 + ck] = o.s4;
    }
}

// ---------------------------------------------------------------------------
// Merged Q/K/V projection, XCD-chunked (R7 form — BEST MEASURED ~<77us).
// R8-R10 bracketed this design: 48KB LDS (KV-fused) -> occupancy kill (107us);
// direct-B from L2 -> exposed latency (122us); BK=32 dbuf -> 2x drain count
// (97us). The 2-barrier BK=64 single-buffer 128^2 block is the local optimum;
// further gains need the 8-phase counted-vmcnt 256^2 template (not attempted:
// new sync structure, reduced payoff at K=1024, ~192-block CU under-fill).
// Remap: lid = (hw&7)*192 + hw>>3 gives each XCD a contiguous lid range;
// decode lid n-fastest, then m, mode slowest. Per-XCD steady working set =
// weight (2MB) + A-tile (256KB) < 4MB L2.
//   lid [0,512): K   lid [512,1024): V   lid [1024,1536): Q
// ---------------------------------------------------------------------------
__global__ __launch_bounds__(256) void proj_kernel(
    const ushort* __restrict__ Qb, const ushort* __restrict__ Cb,
    const ushort* __restrict__ WTbase,
    const float* __restrict__ biasq, const float* __restrict__ biask,
    const float* __restrict__ biasv,
    ushort* __restrict__ Qw, ushort* __restrict__ Kw, ushort* __restrict__ Vtw,
    float scale)
{
    __shared__ ushort As[128 * 64];
    __shared__ ushort Bs[128 * 64];
    const int tid = threadIdx.x;
    const int w = tid >> 6, lane = tid & 63;
    const int ln = tid & 15, quad = (tid >> 4) & 3;
    const int wm = w >> 1, wn = w & 1;

    const int hw = blockIdx.x;
    const int lid = (hw & 7) * 192 + (hw >> 3);   // XCD-contiguous (1536=8*192)
    const int mode = lid >> 9;                    // 0=K, 1=V, 2=Q
    const int rem = lid & 511;
    const int m0 = (rem >> 3) * 128;
    const int n0 = (rem & 7) * 128;
    const ushort* Ag = (mode == 2) ? Qb : Cb;
    const ushort* BT = (mode == 2) ? WTbase : WTbase + (size_t)(1 + mode) * 1048576;

    int offA[4], offB[4], lseg[4];
#pragma unroll
    for (int rr = 0; rr < 4; ++rr) {
        int idx = (rr * 4 + w) * 64 + lane;
        int r = idx >> 3, cst = idx & 7, csrc = cst ^ (r & 7);
        offA[rr] = (m0 + r) * 1024 + csrc * 8;
        offB[rr] = (n0 + r) * 1024 + csrc * 8;
        lseg[rr] = (rr * 4 + w) * 512;
    }

    f32x4 acc[4][4] = {};

    for (int kk = 0; kk < 1024; kk += 64) {
        __syncthreads();
#pragma unroll
        for (int rr = 0; rr < 4; ++rr)
            gll16(&Ag[(size_t)(offA[rr] + kk)], &As[lseg[rr]]);
#pragma unroll
        for (int rr = 0; rr < 4; ++rr)
            gll16(&BT[(size_t)(offB[rr] + kk)], &Bs[lseg[rr]]);
        __syncthreads();

#pragma unroll
        for (int ks = 0; ks < 2; ++ks) {
            short8 af[4], bfr[4];
#pragma unroll
            for (int i = 0; i < 4; ++i)
                af[i] = *(const short8*)&As[(wm * 64 + i * 16 + ln) * 64 +
                                            ((ks * 4 + quad) ^ (ln & 7)) * 8];
#pragma unroll
            for (int j = 0; j < 4; ++j)
                bfr[j] = *(const short8*)&Bs[(wn * 64 + j * 16 + ln) * 64 +
                                             ((ks * 4 + quad) ^ (ln & 7)) * 8];
#pragma unroll
            for (int i = 0; i < 4; ++i)
#pragma unroll
                for (int j = 0; j < 4; ++j)
                    acc[i][j] = MFMA16(af[i], bfr[j], acc[i][j]);
        }
    }

    if (mode == 1) {
        // V: transposed store [b,h,d,t]
#pragma unroll
        for (int j = 0; j < 4; ++j) {
            int n = n0 + wn * 64 + j * 16 + ln;
            int h = n >> 6, d = n & 63;
            float bvv = biasv[n];
#pragma unroll
            for (int i = 0; i < 4; ++i) {
                int mb = m0 + wm * 64 + i * 16 + quad * 4;
                int b = mb >> 11, t = mb & 2047;
                pk4_u o;
                o.u2[0] = pk_bf16(acc[i][j][0] + bvv, acc[i][j][1] + bvv);
                o.u2[1] = pk_bf16(acc[i][j][2] + bvv, acc[i][j][3] + bvv);
                *(short4_t*)&Vtw[(((size_t)((b * 16 + h) * 64 + d)) << 11) + t] = o.s4;
            }
        }
    } else {
        ushort* Out = (mode == 2) ? Qw : Kw;
        const float* bias = (mode == 2) ? biasq : biask;
        float sc = (mode == 2) ? scale : 1.0f;
#pragma unroll
        for (int j = 0; j < 4; ++j) {
            int n = n0 + wn * 64 + j * 16 + ln;
            int h = n >> 6, d = n & 63;
            float bvv = bias[n];
#pragma unroll
            for (int i = 0; i < 4; ++i) {
                int mb = m0 + wm * 64 + i * 16 + quad * 4;
#pragma unroll
                for (int r = 0; r < 4; ++r) {
                    int m = mb + r, b = m >> 11, t = m & 2047;
                    Out[(((size_t)(b * 16 + h) * 2048 + t) << 6) + d] =
                        (ushort)f2b((acc[i][j][r] + bvv) * sc);
                }
            }
        }
    }
}

// ---------------------------------------------------------------------------
// Output projection GEMM, XCD-chunked (R7 form): flat 512 grid,
// lid = (hw&7)*64 + hw>>3; n fastest, m slower. Per-XCD working set =
// Wo^T (2MB) + one A-tile (256KB) < L2.
// ---------------------------------------------------------------------------
__global__ __launch_bounds__(256) void gemm_o_kernel(
    const ushort* __restrict__ Ag, const ushort* __restrict__ BT,
    const float* __restrict__ bias, float* __restrict__ Out)
{
    __shared__ ushort As[128 * 64];
    __shared__ ushort Bs[128 * 64];
    const int tid = threadIdx.x;
    const int w = tid >> 6, lane = tid & 63;
    const int ln = tid & 15, quad = (tid >> 4) & 3;
    const int wm = w >> 1, wn = w & 1;
    const int hw = blockIdx.x;
    const int lid = (hw & 7) * 64 + (hw >> 3);    // XCD-contiguous (512=8*64)
    const int m0 = (lid >> 3) * 128, n0 = (lid & 7) * 128;

    int offA[4], offB[4], lseg[4];
#pragma unroll
    for (int rr = 0; rr < 4; ++rr) {
        int idx = (rr * 4 + w) * 64 + lane;
        int r = idx >> 3, cst = idx & 7, csrc = cst ^ (r & 7);
        offA[rr] = (m0 + r) * 1024 + csrc * 8;
        offB[rr] = (n0 + r) * 1024 + csrc * 8;
        lseg[rr] = (rr * 4 + w) * 512;
    }

    f32x4 acc[4][4] = {};

    for (int kk = 0; kk < 1024; kk += 64) {
        __syncthreads();
#pragma unroll
        for (int rr = 0; rr < 4; ++rr)
            gll16(&Ag[(size_t)(offA[rr] + kk)], &As[lseg[rr]]);
#pragma unroll
        for (int rr = 0; rr < 4; ++rr)
            gll16(&BT[(size_t)(offB[rr] + kk)], &Bs[lseg[rr]]);
        __syncthreads();

#pragma unroll
        for (int ks = 0; ks < 2; ++ks) {
            short8 af[4], bfr[4];
#pragma unroll
            for (int i = 0; i < 4; ++i)
                af[i] = *(const short8*)&As[(wm * 64 + i * 16 + ln) * 64 +
                                            ((ks * 4 + quad) ^ (ln & 7)) * 8];
#pragma unroll
            for (int j = 0; j < 4; ++j)
                bfr[j] = *(const short8*)&Bs[(wn * 64 + j * 16 + ln) * 64 +
                                             ((ks * 4 + quad) ^ (ln & 7)) * 8];
#pragma unroll
            for (int i = 0; i < 4; ++i)
#pragma unroll
                for (int j = 0; j < 4; ++j)
                    acc[i][j] = MFMA16(af[i], bfr[j], acc[i][j]);
        }
    }

#pragma unroll
    for (int j = 0; j < 4; ++j) {
        int n = n0 + wn * 64 + j * 16 + ln;
        float bv = bias[n];
#pragma unroll
        for (int i = 0; i < 4; ++i) {
            int mb = m0 + wm * 64 + i * 16 + quad * 4;
#pragma unroll
            for (int r = 0; r < 4; ++r)
                Out[(size_t)(mb + r) * 1024 + n] = acc[i][j][r] + bv;
        }
    }
}

// ---------------------------------------------------------------------------
// Flash attention v9 (R7 form; 76.8us, ~900 TF effective — matches the
// plain-HIP 8-warp reference ladder endpoint).
// ---------------------------------------------------------------------------
__global__ __launch_bounds__(256, 4) void attn_kernel(
    const ushort* __restrict__ Qw, const ushort* __restrict__ Kw,
    const ushort* __restrict__ Vtw, ushort* __restrict__ attn)
{
    __shared__ ushort Ks[2][4096];      // 64 kv x 64 d, XOR chunk swizzle
    __shared__ ushort Vts[2][4096];     // 64 d  x 64 kv, XOR chunk swizzle

    const int tid = threadIdx.x;
    const int w = tid >> 6, lane = tid & 63;
    const int ln = tid & 15, quad = (tid >> 4) & 3;
    // XCD swizzle (bijective over 1024 = 8*128): xcd = id&7 = bh&7.
    const int id = blockIdx.x;
    const int qt = (id >> 3) & 15;
    const int bh = (id & 7) | ((id >> 7) << 3);
    const int b = bh >> 4, h = bh & 15;

    const ushort* Qg = Qw + (size_t)bh * 131072 + (size_t)qt * 8192;
    const ushort* Kg = Kw + (size_t)bh * 131072;
    const ushort* Vg = Vtw + (size_t)bh * 131072;

    // Q fragments (B-operand of K=32 QK): lane holds Q[q=w*32+qs*16+ln][d]
    short8 bq[2][2];
#pragma unroll
    for (int qs = 0; qs < 2; ++qs)
#pragma unroll
        for (int ks = 0; ks < 2; ++ks)
            bq[qs][ks] = *(const short8*)&Qg[(w * 32 + qs * 16 + ln) * 64 + ks * 32 + quad * 8];

    int offK[2], offV[2], lseg[2];
#pragma unroll
    for (int rr = 0; rr < 2; ++rr) {
        int idx = (rr * 4 + w) * 64 + lane;
        int r = idx >> 3, cst = idx & 7, csrc = cst ^ (r & 7);
        offK[rr] = r * 64 + csrc * 8;
        offV[rr] = r * 2048 + csrc * 8;
        lseg[rr] = (rr * 4 + w) * 512;
    }

    const short8 ones8 = {(short)0x3F80, (short)0x3F80, (short)0x3F80, (short)0x3F80,
                          (short)0x3F80, (short)0x3F80, (short)0x3F80, (short)0x3F80};

    f32x4 Of[2][4] = {};     // O^T: col = q = ln (qs slab), rows = d-local quad*4+r
    f32x4 lac[2] = {};       // col-sums of P: col = q = ln, rows all equal

    // prologue: stage tile 0 into buffer 0 (drained by the barrier below)
#pragma unroll
    for (int rr = 0; rr < 2; ++rr) gll16(&Kg[offK[rr]], &Ks[0][lseg[rr]]);
#pragma unroll
    for (int rr = 0; rr < 2; ++rr) gll16(&Vg[offV[rr]], &Vts[0][lseg[rr]]);
    __syncthreads();

    auto body = [&](int kt, const ushort* Kc, const ushort* Vc,
                    ushort* Kn, ushort* Vn) {
        // issue next tile's async global->LDS loads FIRST; the end-of-body
        // barrier's vmcnt(0) drain then overlaps this tile's compute.
        if (kt < 31) {
#pragma unroll
            for (int rr = 0; rr < 2; ++rr)
                gll16(&Kg[(kt + 1) * 4096 + offK[rr]], &Kn[lseg[rr]]);
#pragma unroll
            for (int rr = 0; rr < 2; ++rr)
                gll16(&Vg[(kt + 1) * 64 + offV[rr]], &Vn[lseg[rr]]);
        }

#pragma unroll
        for (int c = 0; c < 2; ++c) {
            // batch K fragment reads, then a pure-MFMA QK cluster
            short8 a0[2], a1[2];
#pragma unroll
            for (int kb = 0; kb < 2; ++kb) {
                int kv = 2 * c + kb;
                a0[kb] = *(const short8*)&Kc[(kv * 16 + ln) * 64 + (quad ^ (ln & 7)) * 8];
                a1[kb] = *(const short8*)&Kc[(kv * 16 + ln) * 64 + ((4 + quad) ^ (ln & 7)) * 8];
            }
            f32x4 s[2][2];
            __builtin_amdgcn_s_setprio(1);
#pragma unroll
            for (int kb = 0; kb < 2; ++kb)
#pragma unroll
                for (int qs = 0; qs < 2; ++qs) {
                    f32x4 t = {};
                    t = MFMA16(a0[kb], bq[qs][0], t);
                    t = MFMA16(a1[kb], bq[qs][1], t);
                    s[kb][qs] = t;
                }
            __builtin_amdgcn_s_setprio(0);

            // exp2 + hardware pack into CONCATENATED K=32 B-operand
            short8 pf8[2];
#pragma unroll
            for (int qs = 0; qs < 2; ++qs) {
                pk8_u pu;
                pu.u4[0] = pk_bf16(__builtin_amdgcn_exp2f(s[0][qs][0]),
                                   __builtin_amdgcn_exp2f(s[0][qs][1]));
                pu.u4[1] = pk_bf16(__builtin_amdgcn_exp2f(s[0][qs][2]),
                                   __builtin_amdgcn_exp2f(s[0][qs][3]));
                pu.u4[2] = pk_bf16(__builtin_amdgcn_exp2f(s[1][qs][0]),
                                   __builtin_amdgcn_exp2f(s[1][qs][1]));
                pu.u4[3] = pk_bf16(__builtin_amdgcn_exp2f(s[1][qs][2]),
                                   __builtin_amdgcn_exp2f(s[1][qs][3]));
                pf8[qs] = pu.s8;
                lac[qs] = MFMA16(ones8, pu.s8, lac[qs]);   // denominator, K=32
            }

            // batch V fragment reads, then a pure-MFMA PV cluster
            cat8_u av[4];
#pragma unroll
            for (int ds = 0; ds < 4; ++ds) {
                const ushort* vrow = &Vc[(ds * 16 + ln) * 64];
                av[ds].s4[0] = *(const short4_t*)&vrow[(((4 * c + (quad >> 1)) ^ (ln & 7)) * 8) + (quad & 1) * 4];
                av[ds].s4[1] = *(const short4_t*)&vrow[(((4 * c + 2 + (quad >> 1)) ^ (ln & 7)) * 8) + (quad & 1) * 4];
            }
            __builtin_amdgcn_s_setprio(1);
#pragma unroll
            for (int ds = 0; ds < 4; ++ds)
#pragma unroll
                for (int qs = 0; qs < 2; ++qs)
                    Of[qs][ds] = MFMA16(av[ds].s8, pf8[qs], Of[qs][ds]);
            __builtin_amdgcn_s_setprio(0);
        }

        // single barrier per tile: drains next-tile vmcnt (overlapped with the
        // compute above) AND guarantees all waves finished reading this buffer.
        __syncthreads();
    };

    for (int kt = 0; kt < 32; kt += 2) {
        body(kt,     Ks[0], Vts[0], Ks[1], Vts[1]);
        body(kt + 1, Ks[1], Vts[1], Ks[0], Vts[0]);
    }

    // finalize: lane ln owns q = w*32 + qs*16 + ln for both l and O columns
#pragma unroll
    for (int qs = 0; qs < 2; ++qs) {
        float inv = __builtin_amdgcn_rcpf(lac[qs][0]);
        int t = qt * 128 + w * 32 + qs * 16 + ln;
        size_t base = ((size_t)(b * 2048 + t) << 10) + h * 64;
#pragma unroll
        for (int ds = 0; ds < 4; ++ds) {
            uint2 o;
            o.x = pk_bf16(Of[qs][ds][0] * inv, Of[qs][ds][1] * inv);
            o.y = pk_bf16(Of[qs][ds][2] * inv, Of[qs][ds][3] * inv);
            *(uint2*)&attn[base + ds * 16 + quad * 4] = o;
        }
    }
}

// ---------------------------------------------------------------------------
extern "C" void kernel_launch(void* const* d_in, const int* in_sizes, int n_in,
                              void* d_out, int out_size, void* d_ws, size_t ws_size,
                              hipStream_t stream)
{
    const float* query   = (const float*)d_in[0];
    const float* context = (const float*)d_in[1];
    const float* Wq = (const float*)d_in[2];
    const float* bq = (const float*)d_in[3];
    const float* Wk = (const float*)d_in[4];
    const float* bk = (const float*)d_in[5];
    const float* Wv = (const float*)d_in[6];
    const float* bv = (const float*)d_in[7];
    const float* Wo = (const float*)d_in[8];
    const float* bo = (const float*)d_in[9];

    char* ws = (char*)d_ws;
    ushort* WT  = (ushort*)ws;                        // 4 x 2 MB bf16 [n][k]
    ushort* Qb  = (ushort*)(ws + 8388608);            // query bf16; later Aw
    ushort* Qw  = (ushort*)(ws + 25165824);           // [b,h,t,d] (pre-scaled)
    ushort* Kw  = (ushort*)(ws + 41943040);           // [b,h,t,d]
    ushort* Vtw = (ushort*)(ws + 58720256);           // [b,h,d,t]
    ushort* Aw  = Qb;                                 // attn out reuses Qb
    ushort* Cb  = (ushort*)d_out;                     // context bf16 in d_out

    const float SCALE = 0.18033688011112042f;         // log2(e)/sqrt(64)

    cvt_all_kernel<<<dim3(9216), 256, 0, stream>>>(query, context, Qb, Cb,
                                                   Wq, Wk, Wv, Wo, WT);
    proj_kernel<<<dim3(1536), 256, 0, stream>>>(Qb, Cb, WT, bq, bk, bv,
                                                Qw, Kw, Vtw, SCALE);
    attn_kernel<<<dim3(1024), 256, 0, stream>>>(Qw, Kw, Vtw, Aw);
    gemm_o_kernel<<<dim3(512), 256, 0, stream>>>(Aw, WT + 3 * 1048576, bo,
                                                 (float*)d_out);
}